// Round 18
// baseline (257.508 us; speedup 1.0000x reference)
//
#include <hip/hip_runtime.h>
#include <hip/hip_bf16.h>
#include <hip/hip_fp16.h>

#define NN 50000
#define NE 1600000
#define DIM 128
#define NU 10000
#define NB 256           // histogram/scatter chunks
#define SLICE_W 12500    // NN/4 packed-uint8 words per slice
#define NE4 (NE / 4)
#define CHUNK4 ((NE4 + NB - 1) / NB)   // int4 per block
#define NRB 98           // reduce/scan blocks: ceil(NN/512)
#define MM_ROWS 64       // rows per mfma-matmul block iteration

typedef __attribute__((ext_vector_type(8))) _Float16 f16x8;
typedef __attribute__((ext_vector_type(4))) float f32x4;

// Fused per-chunk packed-uint8 histograms: blocks [0,NB) -> dst, [NB,2NB) -> src
__global__ __launch_bounds__(1024) void k_hist(const int4* __restrict__ src4,
                                               const int4* __restrict__ dst4,
                                               unsigned int* __restrict__ histD,
                                               unsigned int* __restrict__ histS) {
    __shared__ unsigned int lh[SLICE_W];   // 50 KB
    for (int i = threadIdx.x; i < SLICE_W; i += 1024) lh[i] = 0u;
    __syncthreads();
    int b = blockIdx.x & (NB - 1);
    const int4* idx4 = (blockIdx.x < NB) ? dst4 : src4;
    unsigned int* out = ((blockIdx.x < NB) ? histD : histS) + (size_t)b * SLICE_W;
    int beg = b * CHUNK4, end = min(beg + CHUNK4, NE4);
    for (int i = beg + threadIdx.x; i < end; i += 1024) {
        int4 v = idx4[i];
        atomicAdd(&lh[v.x >> 2], 1u << ((v.x & 3) * 8));
        atomicAdd(&lh[v.y >> 2], 1u << ((v.y & 3) * 8));
        atomicAdd(&lh[v.z >> 2], 1u << ((v.z & 3) * 8));
        atomicAdd(&lh[v.w >> 2], 1u << ((v.w & 3) * 8));
    }
    __syncthreads();
    for (int i = threadIdx.x; i < SLICE_W; i += 1024) out[i] = lh[i];
}

// 98 blocks x 256 thr: block covers 128 wi (512 nodes); 2-way split of the b-loop.
__global__ __launch_bounds__(256) void k_reduce_norms(const unsigned int* __restrict__ histD,
                                                      const unsigned int* __restrict__ histS,
                                                      int* __restrict__ din,
                                                      float* __restrict__ cs, float* __restrict__ cd,
                                                      int* __restrict__ partials) {
    __shared__ unsigned int part8[128][8];
    __shared__ int red[256];
    int wl = threadIdx.x & 127;
    int g = threadIdx.x >> 7;
    int wi = blockIdx.x * 128 + wl;
    unsigned int d0 = 0, d1 = 0, d2 = 0, d3 = 0, s0 = 0, s1 = 0, s2 = 0, s3 = 0;
    if (wi < SLICE_W) {
        for (int b = g * 128; b < g * 128 + 128; ++b) {
            unsigned int wd = histD[(size_t)b * SLICE_W + wi];
            unsigned int ws = histS[(size_t)b * SLICE_W + wi];
            d0 += wd & 0xFFu; d1 += (wd >> 8) & 0xFFu; d2 += (wd >> 16) & 0xFFu; d3 += wd >> 24;
            s0 += ws & 0xFFu; s1 += (ws >> 8) & 0xFFu; s2 += (ws >> 16) & 0xFFu; s3 += ws >> 24;
        }
    }
    red[threadIdx.x] = (int)(d0 + d1 + d2 + d3);
    if (g == 1) {
        part8[wl][0] = d0; part8[wl][1] = d1; part8[wl][2] = d2; part8[wl][3] = d3;
        part8[wl][4] = s0; part8[wl][5] = s1; part8[wl][6] = s2; part8[wl][7] = s3;
    }
    __syncthreads();
    if (g == 0 && wi < SLICE_W) {
        d0 += part8[wl][0]; d1 += part8[wl][1]; d2 += part8[wl][2]; d3 += part8[wl][3];
        s0 += part8[wl][4]; s1 += part8[wl][5]; s2 += part8[wl][6]; s3 += part8[wl][7];
        int n = wi * 4;
        *(int4*)&din[n] = make_int4(d0, d1, d2, d3);
        float4 vcd, vcs;
        vcd.x = rsqrtf(fmaxf((float)d0, 1.f)); vcd.y = rsqrtf(fmaxf((float)d1, 1.f));
        vcd.z = rsqrtf(fmaxf((float)d2, 1.f)); vcd.w = rsqrtf(fmaxf((float)d3, 1.f));
        vcs.x = rsqrtf(fmaxf((float)s0, 1.f)); vcs.y = rsqrtf(fmaxf((float)s1, 1.f));
        vcs.z = rsqrtf(fmaxf((float)s2, 1.f)); vcs.w = rsqrtf(fmaxf((float)s3, 1.f));
        *(float4*)&cd[n] = vcd;
        *(float4*)&cs[n] = vcs;
    }
    for (int off = 128; off > 0; off >>= 1) {
        if (threadIdx.x < off) red[threadIdx.x] += red[threadIdx.x + off];
        __syncthreads();
    }
    if (threadIdx.x == 0) partials[blockIdx.x] = red[0];
}

// 98 blocks x 128 thr: computes own base from partials, then 512-node scan -> offs
__global__ __launch_bounds__(128) void k_scan3(const int* __restrict__ din,
                                               const int* __restrict__ partials,
                                               int* __restrict__ offs) {
    __shared__ int part[128];
    __shared__ int sbase;
    int t = threadIdx.x;
    part[t] = (t < blockIdx.x) ? partials[t] : 0;
    __syncthreads();
    for (int off = 64; off > 0; off >>= 1) {
        if (t < off) part[t] += part[t + off];
        __syncthreads();
    }
    if (t == 0) sbase = part[0];
    __syncthreads();
    int base = sbase;
    int n0 = blockIdx.x * 512 + t * 4;
    int4 d = make_int4(0, 0, 0, 0);
    if (n0 < NN) d = *(const int4*)&din[n0];
    int tsum = d.x + d.y + d.z + d.w;
    __syncthreads();
    part[t] = tsum;
    __syncthreads();
    for (int off = 1; off < 128; off <<= 1) {
        int v = (t >= off) ? part[t - off] : 0;
        __syncthreads();
        part[t] += v;
        __syncthreads();
    }
    if (n0 < NN) {
        int o = base + part[t] - tsum;
        *(int4*)&offs[n0] = make_int4(o, o + d.x, o + d.x + d.y, o + d.x + d.y + d.z);
    }
}

// rel8[b][n] = sum over b' < b of histD[b'][n]
__global__ __launch_bounds__(256) void k_blockbase(const unsigned int* __restrict__ histD,
                                                   unsigned char* __restrict__ rel8) {
    int n = blockIdx.x * blockDim.x + threadIdx.x;
    if (n >= NN) return;
    int wi = n >> 2, sh = (n & 3) * 8;
    unsigned int run = 0;
    for (int b = 0; b < NB; ++b) {
        rel8[(size_t)b * NN + n] = (unsigned char)run;
        run += (histD[(size_t)b * SLICE_W + wi] >> sh) & 0xFFu;
    }
}

// Atomic-free CSC scatter (uint16 entries)
__global__ __launch_bounds__(1024) void k_scatter2(const int4* __restrict__ src4,
                                                   const int4* __restrict__ dst4,
                                                   const int* __restrict__ offs,
                                                   const unsigned char* __restrict__ rel8,
                                                   unsigned short* __restrict__ csc) {
    __shared__ unsigned int lc[SLICE_W];
    for (int i = threadIdx.x; i < SLICE_W; i += 1024) lc[i] = 0u;
    __syncthreads();
    int b = blockIdx.x;
    const unsigned char* rel = rel8 + (size_t)b * NN;
    int beg = b * CHUNK4, end = min(beg + CHUNK4, NE4);
    for (int i = beg + threadIdx.x; i < end; i += 1024) {
        int4 s = src4[i];
        int4 d = dst4[i];
#pragma unroll
        for (int j = 0; j < 4; ++j) {
            int dd = (j == 0) ? d.x : (j == 1) ? d.y : (j == 2) ? d.z : d.w;
            int ss = (j == 0) ? s.x : (j == 1) ? s.y : (j == 2) ? s.z : s.w;
            int sh = (dd & 3) * 8;
            unsigned int old = atomicAdd(&lc[dd >> 2], 1u << sh);
            int local = (old >> sh) & 0xFF;
            csc[offs[dd] + rel[dd] + local] = (unsigned short)ss;
        }
    }
}

// MFMA matmul: Y[r][:] = fp16((X[r][:] @ W) * cs[r]).
__global__ __launch_bounds__(256) void k_matmul_mfma(const float* __restrict__ X,
                                                     const float* __restrict__ W,
                                                     const float* __restrict__ cs,
                                                     __half* __restrict__ Y, int nrows) {
    __shared__ f16x8 sB[8][4][64];   // [colTile][kChunk][lane] : 32 KB
    __shared__ f16x8 sA[4][4][64];   // [rowTile(wave)][kChunk][lane] : 16 KB
    int t = threadIdx.x;
    for (int e = t; e < 8 * 4 * 64; e += 256) {
        int ct = e >> 8;
        int k0 = (e >> 6) & 3;
        int l = e & 63;
        int c = ct * 16 + (l & 15);
        int kb = k0 * 32 + ((l >> 4) << 3);
        f16x8 frag;
#pragma unroll
        for (int j = 0; j < 8; ++j) frag[j] = (_Float16)W[(size_t)(kb + j) * DIM + c];
        sB[ct][k0][l] = frag;
    }
    int wave = t >> 6;
    int l = t & 63;
    int crow = (l >> 4) * 4;
    int ccol = l & 15;
    int ng = (nrows + MM_ROWS - 1) / MM_ROWS;
    for (int g = blockIdx.x; g < ng; g += gridDim.x) {
        int rbase = g * MM_ROWS;
        __syncthreads();
        for (int e = t; e < 4 * 4 * 64; e += 256) {
            int wt = e >> 8;
            int k0 = (e >> 6) & 3;
            int ll = e & 63;
            int r = min(rbase + wt * 16 + (ll & 15), nrows - 1);
            int kb = k0 * 32 + ((ll >> 4) << 3);
            const float* xp = X + (size_t)r * DIM + kb;
            float4 xa = *(const float4*)xp;
            float4 xb = *(const float4*)(xp + 4);
            f16x8 frag;
            frag[0] = (_Float16)xa.x; frag[1] = (_Float16)xa.y;
            frag[2] = (_Float16)xa.z; frag[3] = (_Float16)xa.w;
            frag[4] = (_Float16)xb.x; frag[5] = (_Float16)xb.y;
            frag[6] = (_Float16)xb.z; frag[7] = (_Float16)xb.w;
            sA[wt][k0][ll] = frag;
        }
        __syncthreads();
        f16x8 a0 = sA[wave][0][l], a1 = sA[wave][1][l];
        f16x8 a2 = sA[wave][2][l], a3 = sA[wave][3][l];
        float csv[4];
#pragma unroll
        for (int j = 0; j < 4; ++j)
            csv[j] = cs[min(rbase + wave * 16 + crow + j, nrows - 1)];
#pragma unroll
        for (int ct = 0; ct < 8; ++ct) {
            f32x4 acc = {0.f, 0.f, 0.f, 0.f};
            acc = __builtin_amdgcn_mfma_f32_16x16x32_f16(a0, sB[ct][0][l], acc, 0, 0, 0);
            acc = __builtin_amdgcn_mfma_f32_16x16x32_f16(a1, sB[ct][1][l], acc, 0, 0, 0);
            acc = __builtin_amdgcn_mfma_f32_16x16x32_f16(a2, sB[ct][2][l], acc, 0, 0, 0);
            acc = __builtin_amdgcn_mfma_f32_16x16x32_f16(a3, sB[ct][3][l], acc, 0, 0, 0);
#pragma unroll
            for (int j = 0; j < 4; ++j) {
                int r = rbase + wave * 16 + crow + j;
                if (r < nrows)
                    Y[(size_t)r * DIM + ct * 16 + ccol] = __float2half(acc[j] * csv[j]);
            }
        }
    }
}

// Full-row aggregate, masked uniform 16-deep: each half-wave covers a fixed
// 32-edge window per iteration -> exactly ceil(deg/32) memory round trips.
__global__ __launch_bounds__(256) void k_aggregate(const __half* __restrict__ hs,
                                                   const unsigned short* __restrict__ csc,
                                                   const int* __restrict__ offs,
                                                   const int* __restrict__ din,
                                                   const float* __restrict__ cd,
                                                   const float* __restrict__ bias,
                                                   float* __restrict__ out) {
    int wid = threadIdx.x >> 6;
    int lane = threadIdx.x & 63;
    int h = lane >> 5;
    int l = lane & 31;
    int d = blockIdx.x * 4 + wid;
    int beg = offs[d];
    int end = beg + din[d];
    const __half* base = hs + l * 4;
    float a0 = 0.f, a1 = 0.f, a2 = 0.f, a3 = 0.f;
    float b0 = 0.f, b1 = 0.f, b2 = 0.f, b3 = 0.f;
    float c0 = 0.f, c1 = 0.f, c2 = 0.f, c3 = 0.f;
    float e0 = 0.f, e1 = 0.f, e2 = 0.f, e3 = 0.f;
    for (int ib = beg; ib < end; ib += 32) {
        int idx[16];
        float msk[16];
#pragma unroll
        for (int j = 0; j < 16; ++j) {
            int i = ib + h + 2 * j;
            bool m = i < end;
            idx[j] = csc[m ? i : beg];
            msk[j] = m ? 1.f : 0.f;
        }
        short4 v[16];
#pragma unroll
        for (int j = 0; j < 16; ++j) v[j] = *(const short4*)(base + (size_t)idx[j] * DIM);
#pragma unroll
        for (int j = 0; j < 16; ++j) {
            float2 x0 = __half22float2(*(const __half2*)&v[j].x);
            float2 x1 = __half22float2(*(const __half2*)&v[j].z);
            float m = msk[j];
            if ((j & 3) == 0) {
                a0 = fmaf(x0.x, m, a0); a1 = fmaf(x0.y, m, a1);
                a2 = fmaf(x1.x, m, a2); a3 = fmaf(x1.y, m, a3);
            } else if ((j & 3) == 1) {
                b0 = fmaf(x0.x, m, b0); b1 = fmaf(x0.y, m, b1);
                b2 = fmaf(x1.x, m, b2); b3 = fmaf(x1.y, m, b3);
            } else if ((j & 3) == 2) {
                c0 = fmaf(x0.x, m, c0); c1 = fmaf(x0.y, m, c1);
                c2 = fmaf(x1.x, m, c2); c3 = fmaf(x1.y, m, c3);
            } else {
                e0 = fmaf(x0.x, m, e0); e1 = fmaf(x0.y, m, e1);
                e2 = fmaf(x1.x, m, e2); e3 = fmaf(x1.y, m, e3);
            }
        }
    }
    a0 += b0 + c0 + e0; a1 += b1 + c1 + e1;
    a2 += b2 + c2 + e2; a3 += b3 + c3 + e3;
    a0 += __shfl(a0, lane ^ 32);
    a1 += __shfl(a1, lane ^ 32);
    a2 += __shfl(a2, lane ^ 32);
    a3 += __shfl(a3, lane ^ 32);
    if (h == 0) {
        float c = cd[d];
        float4 bv = *(const float4*)&bias[l * 4];
        float4 o;
        o.x = fmaxf(fmaf(a0, c, bv.x), 0.f);
        o.y = fmaxf(fmaf(a1, c, bv.y), 0.f);
        o.z = fmaxf(fmaf(a2, c, bv.z), 0.f);
        o.w = fmaxf(fmaf(a3, c, bv.w), 0.f);
        *(float4*)&out[(size_t)d * DIM + l * 4] = o;
    }
}

// R[u][:] = tanh(h[users[u]] @ Ws1 + bs1) @ Ws2 + bs2
__global__ __launch_bounds__(256) void k_sr_head(const float* __restrict__ h,
                                                 const int* __restrict__ users,
                                                 const float* __restrict__ Ws1,
                                                 const float* __restrict__ bs1,
                                                 const float* __restrict__ Ws2,
                                                 const float* __restrict__ bs2,
                                                 float* __restrict__ R, int nu) {
    __shared__ float sW1[DIM * 64];
    __shared__ float sW2[64 * 64];
    __shared__ float sU[4][DIM];
    __shared__ float sT[4][64];
    for (int i = threadIdx.x * 4; i < DIM * 64; i += 256 * 4)
        *(float4*)&sW1[i] = *(const float4*)&Ws1[i];
    for (int i = threadIdx.x * 4; i < 64 * 64; i += 256 * 4)
        *(float4*)&sW2[i] = *(const float4*)&Ws2[i];
    int ul = threadIdx.x >> 6;
    int c = threadIdx.x & 63;
    for (int base = blockIdx.x * 4; base < nu; base += gridDim.x * 4) {
        int u = base + ul;
        __syncthreads();
        if (u < nu) {
            int node = users[u];
            *(float2*)&sU[ul][c * 2] = *(const float2*)&h[(size_t)node * DIM + c * 2];
        }
        __syncthreads();
        float t = 0.f;
        if (u < nu) {
            float acc = bs1[c];
#pragma unroll 8
            for (int k = 0; k < DIM; ++k) acc = fmaf(sU[ul][k], sW1[k * 64 + c], acc);
            t = tanhf(acc);
        }
        sT[ul][c] = t;
        __syncthreads();
        if (u < nu) {
            float acc = bs2[c];
#pragma unroll 8
            for (int k = 0; k < 64; ++k) acc = fmaf(sT[ul][k], sW2[k * 64 + c], acc);
            R[(size_t)u * 64 + c] = acc;
        }
    }
}

extern "C" void kernel_launch(void* const* d_in, const int* in_sizes, int n_in,
                              void* d_out, int out_size, void* d_ws, size_t ws_size,
                              hipStream_t stream) {
    const float* features = (const float*)d_in[0];
    const float* W0  = (const float*)d_in[1];
    const float* b0  = (const float*)d_in[2];
    const float* W1  = (const float*)d_in[3];
    const float* b1  = (const float*)d_in[4];
    const float* Ws1 = (const float*)d_in[5];
    const float* bs1 = (const float*)d_in[6];
    const float* Ws2 = (const float*)d_in[7];
    const float* bs2 = (const float*)d_in[8];
    const int* src   = (const int*)d_in[9];
    const int* dst   = (const int*)d_in[10];
    const int* users = (const int*)d_in[11];

    float* R = (float*)d_out;
    float* H = (float*)d_out + (size_t)NU * 64;

    char* ws = (char*)d_ws;
    __half* hsA  = (__half*)(ws + 0);                      // 12.8 MB
    unsigned int* histD = (unsigned int*)(ws + 0);         // 12.8 MB (256 x 50000B)
    unsigned int* histS = (unsigned int*)(ws + 12800000);  // 12.8 MB
    unsigned char* rel8 = (unsigned char*)(ws + 12800000); // 12.8 MB (overlays dead histS)
    unsigned short* csc = (unsigned short*)(ws + 25600000);//  3.2 MB (uint16 ids)
    int*   din   = (int*)  (ws + 28800000);
    float* cs    = (float*)(ws + 29000000);
    float* cd    = (float*)(ws + 29200000);
    int*   offs  = (int*)  (ws + 29400000);
    int*   partials = (int*)(ws + 29600000);

    k_hist<<<2 * NB, 1024, 0, stream>>>((const int4*)src, (const int4*)dst, histD, histS);
    k_reduce_norms<<<NRB, 256, 0, stream>>>(histD, histS, din, cs, cd, partials);
    k_scan3<<<NRB, 128, 0, stream>>>(din, partials, offs);
    k_blockbase<<<(NN + 255) / 256, 256, 0, stream>>>(histD, rel8);
    k_scatter2<<<NB, 1024, 0, stream>>>((const int4*)src, (const int4*)dst, offs, rel8, csc);

    // layer 1
    k_matmul_mfma<<<782, 256, 0, stream>>>(features, W0, cs, hsA, NN);
    k_aggregate<<<12500, 256, 0, stream>>>(hsA, csc, offs, din, cd, b0, H);

    // layer 2
    k_matmul_mfma<<<782, 256, 0, stream>>>(H, W1, cs, hsA, NN);
    k_aggregate<<<12500, 256, 0, stream>>>(hsA, csc, offs, din, cd, b1, H);

    // SR head
    k_sr_head<<<625, 256, 0, stream>>>(H, users, Ws1, bs1, Ws2, bs2, R, NU);
}

// Round 19
// 246.996 us; speedup vs baseline: 1.0426x; 1.0426x over previous
//
#include <hip/hip_runtime.h>
#include <hip/hip_bf16.h>
#include <hip/hip_fp16.h>

#define NN 50000
#define NE 1600000
#define DIM 128
#define NU 10000
#define NB 256           // histogram/scatter chunks
#define SLICE_W 12500    // NN/4 packed-uint8 words per slice
#define NE4 (NE / 4)
#define CHUNK4 ((NE4 + NB - 1) / NB)   // int4 per block
#define NRB 98           // reduce/scan blocks: ceil(NN/512)
#define MM_ROWS 64       // rows per mfma-matmul block iteration

typedef __attribute__((ext_vector_type(8))) _Float16 f16x8;
typedef __attribute__((ext_vector_type(4))) float f32x4;

// Fused per-chunk packed-uint8 histograms: blocks [0,NB) -> dst, [NB,2NB) -> src
__global__ __launch_bounds__(1024) void k_hist(const int4* __restrict__ src4,
                                               const int4* __restrict__ dst4,
                                               unsigned int* __restrict__ histD,
                                               unsigned int* __restrict__ histS) {
    __shared__ unsigned int lh[SLICE_W];   // 50 KB
    for (int i = threadIdx.x; i < SLICE_W; i += 1024) lh[i] = 0u;
    __syncthreads();
    int b = blockIdx.x & (NB - 1);
    const int4* idx4 = (blockIdx.x < NB) ? dst4 : src4;
    unsigned int* out = ((blockIdx.x < NB) ? histD : histS) + (size_t)b * SLICE_W;
    int beg = b * CHUNK4, end = min(beg + CHUNK4, NE4);
    for (int i = beg + threadIdx.x; i < end; i += 1024) {
        int4 v = idx4[i];
        atomicAdd(&lh[v.x >> 2], 1u << ((v.x & 3) * 8));
        atomicAdd(&lh[v.y >> 2], 1u << ((v.y & 3) * 8));
        atomicAdd(&lh[v.z >> 2], 1u << ((v.z & 3) * 8));
        atomicAdd(&lh[v.w >> 2], 1u << ((v.w & 3) * 8));
    }
    __syncthreads();
    for (int i = threadIdx.x; i < SLICE_W; i += 1024) out[i] = lh[i];
}

// 98 blocks x 256 thr: block covers 128 wi (512 nodes); 2-way split of the b-loop.
__global__ __launch_bounds__(256) void k_reduce_norms(const unsigned int* __restrict__ histD,
                                                      const unsigned int* __restrict__ histS,
                                                      int* __restrict__ din,
                                                      float* __restrict__ cs, float* __restrict__ cd,
                                                      int* __restrict__ partials) {
    __shared__ unsigned int part8[128][8];
    __shared__ int red[256];
    int wl = threadIdx.x & 127;
    int g = threadIdx.x >> 7;
    int wi = blockIdx.x * 128 + wl;
    unsigned int d0 = 0, d1 = 0, d2 = 0, d3 = 0, s0 = 0, s1 = 0, s2 = 0, s3 = 0;
    if (wi < SLICE_W) {
        for (int b = g * 128; b < g * 128 + 128; ++b) {
            unsigned int wd = histD[(size_t)b * SLICE_W + wi];
            unsigned int ws = histS[(size_t)b * SLICE_W + wi];
            d0 += wd & 0xFFu; d1 += (wd >> 8) & 0xFFu; d2 += (wd >> 16) & 0xFFu; d3 += wd >> 24;
            s0 += ws & 0xFFu; s1 += (ws >> 8) & 0xFFu; s2 += (ws >> 16) & 0xFFu; s3 += ws >> 24;
        }
    }
    red[threadIdx.x] = (int)(d0 + d1 + d2 + d3);
    if (g == 1) {
        part8[wl][0] = d0; part8[wl][1] = d1; part8[wl][2] = d2; part8[wl][3] = d3;
        part8[wl][4] = s0; part8[wl][5] = s1; part8[wl][6] = s2; part8[wl][7] = s3;
    }
    __syncthreads();
    if (g == 0 && wi < SLICE_W) {
        d0 += part8[wl][0]; d1 += part8[wl][1]; d2 += part8[wl][2]; d3 += part8[wl][3];
        s0 += part8[wl][4]; s1 += part8[wl][5]; s2 += part8[wl][6]; s3 += part8[wl][7];
        int n = wi * 4;
        *(int4*)&din[n] = make_int4(d0, d1, d2, d3);
        float4 vcd, vcs;
        vcd.x = rsqrtf(fmaxf((float)d0, 1.f)); vcd.y = rsqrtf(fmaxf((float)d1, 1.f));
        vcd.z = rsqrtf(fmaxf((float)d2, 1.f)); vcd.w = rsqrtf(fmaxf((float)d3, 1.f));
        vcs.x = rsqrtf(fmaxf((float)s0, 1.f)); vcs.y = rsqrtf(fmaxf((float)s1, 1.f));
        vcs.z = rsqrtf(fmaxf((float)s2, 1.f)); vcs.w = rsqrtf(fmaxf((float)s3, 1.f));
        *(float4*)&cd[n] = vcd;
        *(float4*)&cs[n] = vcs;
    }
    for (int off = 128; off > 0; off >>= 1) {
        if (threadIdx.x < off) red[threadIdx.x] += red[threadIdx.x + off];
        __syncthreads();
    }
    if (threadIdx.x == 0) partials[blockIdx.x] = red[0];
}

// 98 blocks x 128 thr: computes own base from partials, then 512-node scan -> offs
__global__ __launch_bounds__(128) void k_scan3(const int* __restrict__ din,
                                               const int* __restrict__ partials,
                                               int* __restrict__ offs) {
    __shared__ int part[128];
    __shared__ int sbase;
    int t = threadIdx.x;
    part[t] = (t < blockIdx.x) ? partials[t] : 0;
    __syncthreads();
    for (int off = 64; off > 0; off >>= 1) {
        if (t < off) part[t] += part[t + off];
        __syncthreads();
    }
    if (t == 0) sbase = part[0];
    __syncthreads();
    int base = sbase;
    int n0 = blockIdx.x * 512 + t * 4;
    int4 d = make_int4(0, 0, 0, 0);
    if (n0 < NN) d = *(const int4*)&din[n0];
    int tsum = d.x + d.y + d.z + d.w;
    __syncthreads();
    part[t] = tsum;
    __syncthreads();
    for (int off = 1; off < 128; off <<= 1) {
        int v = (t >= off) ? part[t - off] : 0;
        __syncthreads();
        part[t] += v;
        __syncthreads();
    }
    if (n0 < NN) {
        int o = base + part[t] - tsum;
        *(int4*)&offs[n0] = make_int4(o, o + d.x, o + d.x + d.y, o + d.x + d.y + d.z);
    }
}

// rel8[b][n] = sum over b' < b of histD[b'][n]
__global__ __launch_bounds__(256) void k_blockbase(const unsigned int* __restrict__ histD,
                                                   unsigned char* __restrict__ rel8) {
    int n = blockIdx.x * blockDim.x + threadIdx.x;
    if (n >= NN) return;
    int wi = n >> 2, sh = (n & 3) * 8;
    unsigned int run = 0;
    for (int b = 0; b < NB; ++b) {
        rel8[(size_t)b * NN + n] = (unsigned char)run;
        run += (histD[(size_t)b * SLICE_W + wi] >> sh) & 0xFFu;
    }
}

// Atomic-free CSC scatter (uint16 entries)
__global__ __launch_bounds__(1024) void k_scatter2(const int4* __restrict__ src4,
                                                   const int4* __restrict__ dst4,
                                                   const int* __restrict__ offs,
                                                   const unsigned char* __restrict__ rel8,
                                                   unsigned short* __restrict__ csc) {
    __shared__ unsigned int lc[SLICE_W];
    for (int i = threadIdx.x; i < SLICE_W; i += 1024) lc[i] = 0u;
    __syncthreads();
    int b = blockIdx.x;
    const unsigned char* rel = rel8 + (size_t)b * NN;
    int beg = b * CHUNK4, end = min(beg + CHUNK4, NE4);
    for (int i = beg + threadIdx.x; i < end; i += 1024) {
        int4 s = src4[i];
        int4 d = dst4[i];
#pragma unroll
        for (int j = 0; j < 4; ++j) {
            int dd = (j == 0) ? d.x : (j == 1) ? d.y : (j == 2) ? d.z : d.w;
            int ss = (j == 0) ? s.x : (j == 1) ? s.y : (j == 2) ? s.z : s.w;
            int sh = (dd & 3) * 8;
            unsigned int old = atomicAdd(&lc[dd >> 2], 1u << sh);
            int local = (old >> sh) & 0xFF;
            csc[offs[dd] + rel[dd] + local] = (unsigned short)ss;
        }
    }
}

// MFMA matmul: Y[r][:] = fp16((X[r][:] @ W) * cs[r]).
__global__ __launch_bounds__(256) void k_matmul_mfma(const float* __restrict__ X,
                                                     const float* __restrict__ W,
                                                     const float* __restrict__ cs,
                                                     __half* __restrict__ Y, int nrows) {
    __shared__ f16x8 sB[8][4][64];   // [colTile][kChunk][lane] : 32 KB
    __shared__ f16x8 sA[4][4][64];   // [rowTile(wave)][kChunk][lane] : 16 KB
    int t = threadIdx.x;
    for (int e = t; e < 8 * 4 * 64; e += 256) {
        int ct = e >> 8;
        int k0 = (e >> 6) & 3;
        int l = e & 63;
        int c = ct * 16 + (l & 15);
        int kb = k0 * 32 + ((l >> 4) << 3);
        f16x8 frag;
#pragma unroll
        for (int j = 0; j < 8; ++j) frag[j] = (_Float16)W[(size_t)(kb + j) * DIM + c];
        sB[ct][k0][l] = frag;
    }
    int wave = t >> 6;
    int l = t & 63;
    int crow = (l >> 4) * 4;
    int ccol = l & 15;
    int ng = (nrows + MM_ROWS - 1) / MM_ROWS;
    for (int g = blockIdx.x; g < ng; g += gridDim.x) {
        int rbase = g * MM_ROWS;
        __syncthreads();
        for (int e = t; e < 4 * 4 * 64; e += 256) {
            int wt = e >> 8;
            int k0 = (e >> 6) & 3;
            int ll = e & 63;
            int r = min(rbase + wt * 16 + (ll & 15), nrows - 1);
            int kb = k0 * 32 + ((ll >> 4) << 3);
            const float* xp = X + (size_t)r * DIM + kb;
            float4 xa = *(const float4*)xp;
            float4 xb = *(const float4*)(xp + 4);
            f16x8 frag;
            frag[0] = (_Float16)xa.x; frag[1] = (_Float16)xa.y;
            frag[2] = (_Float16)xa.z; frag[3] = (_Float16)xa.w;
            frag[4] = (_Float16)xb.x; frag[5] = (_Float16)xb.y;
            frag[6] = (_Float16)xb.z; frag[7] = (_Float16)xb.w;
            sA[wt][k0][ll] = frag;
        }
        __syncthreads();
        f16x8 a0 = sA[wave][0][l], a1 = sA[wave][1][l];
        f16x8 a2 = sA[wave][2][l], a3 = sA[wave][3][l];
        float csv[4];
#pragma unroll
        for (int j = 0; j < 4; ++j)
            csv[j] = cs[min(rbase + wave * 16 + crow + j, nrows - 1)];
#pragma unroll
        for (int ct = 0; ct < 8; ++ct) {
            f32x4 acc = {0.f, 0.f, 0.f, 0.f};
            acc = __builtin_amdgcn_mfma_f32_16x16x32_f16(a0, sB[ct][0][l], acc, 0, 0, 0);
            acc = __builtin_amdgcn_mfma_f32_16x16x32_f16(a1, sB[ct][1][l], acc, 0, 0, 0);
            acc = __builtin_amdgcn_mfma_f32_16x16x32_f16(a2, sB[ct][2][l], acc, 0, 0, 0);
            acc = __builtin_amdgcn_mfma_f32_16x16x32_f16(a3, sB[ct][3][l], acc, 0, 0, 0);
#pragma unroll
            for (int j = 0; j < 4; ++j) {
                int r = rbase + wave * 16 + crow + j;
                if (r < nrows)
                    Y[(size_t)r * DIM + ct * 16 + ccol] = __float2half(acc[j] * csv[j]);
            }
        }
    }
}

// Full-row aggregate, 8-deep edge unroll (R12/R16-proven)
__global__ __launch_bounds__(256) void k_aggregate(const __half* __restrict__ hs,
                                                   const unsigned short* __restrict__ csc,
                                                   const int* __restrict__ offs,
                                                   const int* __restrict__ din,
                                                   const float* __restrict__ cd,
                                                   const float* __restrict__ bias,
                                                   float* __restrict__ out) {
    int wid = threadIdx.x >> 6;
    int lane = threadIdx.x & 63;
    int h = lane >> 5;
    int l = lane & 31;
    int d = blockIdx.x * 4 + wid;
    int beg = offs[d];
    int end = beg + din[d];
    const __half* base = hs + l * 4;
    float a0 = 0.f, a1 = 0.f, a2 = 0.f, a3 = 0.f;
    float b0 = 0.f, b1 = 0.f, b2 = 0.f, b3 = 0.f;
    float c0 = 0.f, c1 = 0.f, c2 = 0.f, c3 = 0.f;
    float e0 = 0.f, e1 = 0.f, e2 = 0.f, e3 = 0.f;
    int i = beg + h;
    for (; i + 14 < end; i += 16) {
        int sI[8];
#pragma unroll
        for (int j = 0; j < 8; ++j) sI[j] = csc[i + 2 * j];
        short4 vI[8];
#pragma unroll
        for (int j = 0; j < 8; ++j) vI[j] = *(const short4*)(base + (size_t)sI[j] * DIM);
#pragma unroll
        for (int j = 0; j < 8; j += 4) {
            float2 x0 = __half22float2(*(const __half2*)&vI[j].x);
            float2 x1 = __half22float2(*(const __half2*)&vI[j].z);
            float2 y0 = __half22float2(*(const __half2*)&vI[j + 1].x);
            float2 y1 = __half22float2(*(const __half2*)&vI[j + 1].z);
            float2 z0 = __half22float2(*(const __half2*)&vI[j + 2].x);
            float2 z1 = __half22float2(*(const __half2*)&vI[j + 2].z);
            float2 w0 = __half22float2(*(const __half2*)&vI[j + 3].x);
            float2 w1 = __half22float2(*(const __half2*)&vI[j + 3].z);
            a0 += x0.x; a1 += x0.y; a2 += x1.x; a3 += x1.y;
            b0 += y0.x; b1 += y0.y; b2 += y1.x; b3 += y1.y;
            c0 += z0.x; c1 += z0.y; c2 += z1.x; c3 += z1.y;
            e0 += w0.x; e1 += w0.y; e2 += w1.x; e3 += w1.y;
        }
    }
    for (; i + 6 < end; i += 8) {
        int s0 = csc[i], s1 = csc[i + 2], s2 = csc[i + 4], s3 = csc[i + 6];
        short4 v0 = *(const short4*)(base + (size_t)s0 * DIM);
        short4 v1 = *(const short4*)(base + (size_t)s1 * DIM);
        short4 v2 = *(const short4*)(base + (size_t)s2 * DIM);
        short4 v3 = *(const short4*)(base + (size_t)s3 * DIM);
        float2 x0 = __half22float2(*(const __half2*)&v0.x);
        float2 x1 = __half22float2(*(const __half2*)&v0.z);
        float2 y0 = __half22float2(*(const __half2*)&v1.x);
        float2 y1 = __half22float2(*(const __half2*)&v1.z);
        float2 z0 = __half22float2(*(const __half2*)&v2.x);
        float2 z1 = __half22float2(*(const __half2*)&v2.z);
        float2 w0 = __half22float2(*(const __half2*)&v3.x);
        float2 w1 = __half22float2(*(const __half2*)&v3.z);
        a0 += x0.x; a1 += x0.y; a2 += x1.x; a3 += x1.y;
        b0 += y0.x; b1 += y0.y; b2 += y1.x; b3 += y1.y;
        c0 += z0.x; c1 += z0.y; c2 += z1.x; c3 += z1.y;
        e0 += w0.x; e1 += w0.y; e2 += w1.x; e3 += w1.y;
    }
    for (; i < end; i += 2) {
        int s = csc[i];
        short4 v = *(const short4*)(base + (size_t)s * DIM);
        float2 x0 = __half22float2(*(const __half2*)&v.x);
        float2 x1 = __half22float2(*(const __half2*)&v.z);
        a0 += x0.x; a1 += x0.y; a2 += x1.x; a3 += x1.y;
    }
    a0 += b0 + c0 + e0; a1 += b1 + c1 + e1;
    a2 += b2 + c2 + e2; a3 += b3 + c3 + e3;
    a0 += __shfl(a0, lane ^ 32);
    a1 += __shfl(a1, lane ^ 32);
    a2 += __shfl(a2, lane ^ 32);
    a3 += __shfl(a3, lane ^ 32);
    if (h == 0) {
        float c = cd[d];
        float4 bv = *(const float4*)&bias[l * 4];
        float4 o;
        o.x = fmaxf(fmaf(a0, c, bv.x), 0.f);
        o.y = fmaxf(fmaf(a1, c, bv.y), 0.f);
        o.z = fmaxf(fmaf(a2, c, bv.z), 0.f);
        o.w = fmaxf(fmaf(a3, c, bv.w), 0.f);
        *(float4*)&out[(size_t)d * DIM + l * 4] = o;
    }
}

// R[u][:] = tanh(h[users[u]] @ Ws1 + bs1) @ Ws2 + bs2
__global__ __launch_bounds__(256) void k_sr_head(const float* __restrict__ h,
                                                 const int* __restrict__ users,
                                                 const float* __restrict__ Ws1,
                                                 const float* __restrict__ bs1,
                                                 const float* __restrict__ Ws2,
                                                 const float* __restrict__ bs2,
                                                 float* __restrict__ R, int nu) {
    __shared__ float sW1[DIM * 64];
    __shared__ float sW2[64 * 64];
    __shared__ float sU[4][DIM];
    __shared__ float sT[4][64];
    for (int i = threadIdx.x * 4; i < DIM * 64; i += 256 * 4)
        *(float4*)&sW1[i] = *(const float4*)&Ws1[i];
    for (int i = threadIdx.x * 4; i < 64 * 64; i += 256 * 4)
        *(float4*)&sW2[i] = *(const float4*)&Ws2[i];
    int ul = threadIdx.x >> 6;
    int c = threadIdx.x & 63;
    for (int base = blockIdx.x * 4; base < nu; base += gridDim.x * 4) {
        int u = base + ul;
        __syncthreads();
        if (u < nu) {
            int node = users[u];
            *(float2*)&sU[ul][c * 2] = *(const float2*)&h[(size_t)node * DIM + c * 2];
        }
        __syncthreads();
        float t = 0.f;
        if (u < nu) {
            float acc = bs1[c];
#pragma unroll 8
            for (int k = 0; k < DIM; ++k) acc = fmaf(sU[ul][k], sW1[k * 64 + c], acc);
            t = tanhf(acc);
        }
        sT[ul][c] = t;
        __syncthreads();
        if (u < nu) {
            float acc = bs2[c];
#pragma unroll 8
            for (int k = 0; k < 64; ++k) acc = fmaf(sT[ul][k], sW2[k * 64 + c], acc);
            R[(size_t)u * 64 + c] = acc;
        }
    }
}

extern "C" void kernel_launch(void* const* d_in, const int* in_sizes, int n_in,
                              void* d_out, int out_size, void* d_ws, size_t ws_size,
                              hipStream_t stream) {
    const float* features = (const float*)d_in[0];
    const float* W0  = (const float*)d_in[1];
    const float* b0  = (const float*)d_in[2];
    const float* W1  = (const float*)d_in[3];
    const float* b1  = (const float*)d_in[4];
    const float* Ws1 = (const float*)d_in[5];
    const float* bs1 = (const float*)d_in[6];
    const float* Ws2 = (const float*)d_in[7];
    const float* bs2 = (const float*)d_in[8];
    const int* src   = (const int*)d_in[9];
    const int* dst   = (const int*)d_in[10];
    const int* users = (const int*)d_in[11];

    float* R = (float*)d_out;
    float* H = (float*)d_out + (size_t)NU * 64;

    char* ws = (char*)d_ws;
    __half* hsA  = (__half*)(ws + 0);                      // 12.8 MB
    unsigned int* histD = (unsigned int*)(ws + 0);         // 12.8 MB (256 x 50000B)
    unsigned int* histS = (unsigned int*)(ws + 12800000);  // 12.8 MB
    unsigned char* rel8 = (unsigned char*)(ws + 12800000); // 12.8 MB (overlays dead histS)
    unsigned short* csc = (unsigned short*)(ws + 25600000);//  3.2 MB (uint16 ids)
    int*   din   = (int*)  (ws + 28800000);
    float* cs    = (float*)(ws + 29000000);
    float* cd    = (float*)(ws + 29200000);
    int*   offs  = (int*)  (ws + 29400000);
    int*   partials = (int*)(ws + 29600000);

    k_hist<<<2 * NB, 1024, 0, stream>>>((const int4*)src, (const int4*)dst, histD, histS);
    k_reduce_norms<<<NRB, 256, 0, stream>>>(histD, histS, din, cs, cd, partials);
    k_scan3<<<NRB, 128, 0, stream>>>(din, partials, offs);
    k_blockbase<<<(NN + 255) / 256, 256, 0, stream>>>(histD, rel8);
    k_scatter2<<<NB, 1024, 0, stream>>>((const int4*)src, (const int4*)dst, offs, rel8, csc);

    // layer 1
    k_matmul_mfma<<<782, 256, 0, stream>>>(features, W0, cs, hsA, NN);
    k_aggregate<<<12500, 256, 0, stream>>>(hsA, csc, offs, din, cd, b0, H);

    // layer 2
    k_matmul_mfma<<<782, 256, 0, stream>>>(H, W1, cs, hsA, NN);
    k_aggregate<<<12500, 256, 0, stream>>>(hsA, csc, offs, din, cd, b1, H);

    // SR head
    k_sr_head<<<625, 256, 0, stream>>>(H, users, Ws1, bs1, Ws2, bs2, R, NU);
}